// Round 2
// baseline (130.284 us; speedup 1.0000x reference)
//
#include <hip/hip_runtime.h>
#include <hip/hip_bf16.h>

#define N_TOTAL 4096
#define C_DIM 256
#define K_NEG 128
#define HW 1024
#define TEMP_INV (1.0f / 0.07f)

typedef _Float16 h8 __attribute__((ext_vector_type(8)));

// ---------------------------------------------------------------------------
// Kernel 1: normalize over channel dim + transpose [B,C,HW] -> [N,C] f16.
// 128 blocks: blocks 0..63 handle feat_q, 64..127 handle feat_k.
// Each block: 64 consecutive rows (spatial positions), all 256 channels.
// ---------------------------------------------------------------------------
__global__ __launch_bounds__(256) void norm_tr_kernel(
    const float* __restrict__ fq, const float* __restrict__ fk,
    _Float16* __restrict__ qh, _Float16* __restrict__ kh) {
  const int bid = blockIdx.x;
  const float* in = (bid & 64) ? fk : fq;
  _Float16* out = (bid & 64) ? kh : qh;
  const int blk = bid & 63;
  const int n0 = blk * 64;            // first global row of this tile
  const int b = n0 / HW;
  const int s0 = n0 % HW;
  const float* base = in + (size_t)b * C_DIM * HW + s0;

  const int t = threadIdx.x;
  const int lane = t & 63;            // spatial offset within tile
  const int w = t >> 6;               // wave id: channel quarter

  __shared__ float pss[4][64];
  __shared__ float tile[64][65];      // [c_local][s], padded

  // phase 1: sum of squares over channels (each wave covers 64 channels)
  float ss = 0.f;
#pragma unroll 8
  for (int i = 0; i < 64; ++i) {
    float v = base[(size_t)(w * 64 + i) * HW + lane];
    ss += v * v;
  }
  pss[w][lane] = ss;
  __syncthreads();
  float tot = pss[0][lane] + pss[1][lane] + pss[2][lane] + pss[3][lane];
  float inv = 1.0f / fmaxf(sqrtf(tot), 1e-12f);   // matches eps=1e-12

  // phase 2: transpose 64x64 channel chunks through LDS, write f16 [N,C]
  for (int cc = 0; cc < 4; ++cc) {
#pragma unroll
    for (int i = 0; i < 16; ++i) {
      int cl = w * 16 + i;
      tile[cl][lane] = base[(size_t)(cc * 64 + cl) * HW + lane] * inv;
    }
    __syncthreads();
#pragma unroll
    for (int i = 0; i < 16; ++i) {
      int row = w * 16 + i;
      out[(size_t)(n0 + row) * C_DIM + cc * 64 + lane] =
          (_Float16)tile[lane][row];
    }
    __syncthreads();
  }
}

// ---------------------------------------------------------------------------
// Kernel 2: per-row InfoNCE. One block per row n. 256 threads = 4 waves.
// 8 lanes per dot-product (8 dots concurrently per wave): lane holds 32
// channels of q in f32 registers; k rows streamed as 16B f16 loads.
// ---------------------------------------------------------------------------
__global__ __launch_bounds__(256) void nce_kernel(
    const _Float16* __restrict__ qh, const _Float16* __restrict__ kh,
    const int* __restrict__ neg, float* __restrict__ out) {
  const int n = blockIdx.x;
  const int t = threadIdx.x;
  const int lane = t & 63;
  const int w = t >> 6;
  const int sub = lane & 7;           // position within 8-lane dot group
  const int unit = w * 8 + (lane >> 3);  // 0..31 dot units

  __shared__ float sneg[K_NEG];
  __shared__ float s_lpos;

  // load this lane's q chunk: channels [sub*32, sub*32+32), convert to f32
  const h8* qrow = (const h8*)(qh + (size_t)n * C_DIM) + sub * 4;
  float qf[32];
#pragma unroll
  for (int i = 0; i < 4; ++i) {
    h8 qv = qrow[i];
#pragma unroll
    for (int j = 0; j < 8; ++j) qf[i * 8 + j] = (float)qv[j];
  }

  auto dot8 = [&](int r) -> float {
    const h8* kr = (const h8*)(kh + (size_t)r * C_DIM) + sub * 4;
    float acc = 0.f;
#pragma unroll
    for (int i = 0; i < 4; ++i) {
      h8 kv = kr[i];
#pragma unroll
      for (int j = 0; j < 8; ++j) acc = fmaf((float)kv[j], qf[i * 8 + j], acc);
    }
    acc += __shfl_xor(acc, 1);
    acc += __shfl_xor(acc, 2);
    acc += __shfl_xor(acc, 4);
    return acc;
  };

  // 128 negatives: 4 rounds x 32 units
#pragma unroll
  for (int rnd = 0; rnd < 4; ++rnd) {
    int j = rnd * 32 + unit;
    int r = neg[(size_t)n * K_NEG + j];
    r += (r >= n) ? 1 : 0;            // self-exclusion shift
    float d = dot8(r);
    if (sub == 0) sneg[j] = d;
  }
  // positive logit (unit 0 only; lanes 0..7 of wave 0, shfl stays in-group)
  if (unit == 0) {
    float d = dot8(n);
    if (sub == 0) s_lpos = d;
  }
  __syncthreads();

  // wave 0: logsumexp over 129 logits
  if (w == 0) {
    float lp = s_lpos * TEMP_INV;
    float x1 = sneg[lane] * TEMP_INV;
    float x2 = sneg[lane + 64] * TEMP_INV;
    float m = fmaxf(fmaxf(x1, x2), lp);
#pragma unroll
    for (int off = 32; off; off >>= 1) m = fmaxf(m, __shfl_xor(m, off));
    float s = __expf(x1 - m) + __expf(x2 - m);
#pragma unroll
    for (int off = 32; off; off >>= 1) s += __shfl_xor(s, off);
    if (lane == 0) {
      s += __expf(lp - m);            // positive counted exactly once
      float loss = m + __logf(s) - lp;
      atomicAdd(out, loss * (1.0f / N_TOTAL));
    }
  }
}

extern "C" void kernel_launch(void* const* d_in, const int* in_sizes, int n_in,
                              void* d_out, int out_size, void* d_ws,
                              size_t ws_size, hipStream_t stream) {
  const float* fq = (const float*)d_in[0];
  const float* fk = (const float*)d_in[1];
  const int* neg = (const int*)d_in[2];
  float* out = (float*)d_out;

  _Float16* qh = (_Float16*)d_ws;                       // 2 MiB
  _Float16* kh = qh + (size_t)N_TOTAL * C_DIM;          // 2 MiB

  hipMemsetAsync(d_out, 0, sizeof(float), stream);      // harness poisons 0xAA
  hipLaunchKernelGGL(norm_tr_kernel, dim3(128), dim3(256), 0, stream,
                     fq, fk, qh, kh);
  hipLaunchKernelGGL(nce_kernel, dim3(N_TOTAL), dim3(256), 0, stream,
                     qh, kh, neg, out);
}

// Round 3
// 125.868 us; speedup vs baseline: 1.0351x; 1.0351x over previous
//
#include <hip/hip_runtime.h>
#include <hip/hip_bf16.h>

#define N_TOTAL 4096
#define C_DIM 256
#define K_NEG 128
#define HW 1024
#define TEMP_INV (1.0f / 0.07f)

typedef _Float16 h8 __attribute__((ext_vector_type(8)));

// ---------------------------------------------------------------------------
// Kernel 1a: per-row sum of squares. 512 blocks = 2 tensors x 64 spatial
// chunks x 4 channel quarters. atomicAdd partials into ss[2][4096].
// ---------------------------------------------------------------------------
__global__ __launch_bounds__(256) void ss_kernel(
    const float* __restrict__ fq, const float* __restrict__ fk,
    float* __restrict__ ss) {
  const int bid = blockIdx.x;
  const int tensor = bid >> 8;        // 0=q, 1=k
  const int sp = (bid >> 2) & 63;     // spatial chunk of 64 rows
  const int cc = bid & 3;             // channel quarter (64 channels)
  const float* in = tensor ? fk : fq;
  const int n0 = sp * 64;
  const int b = n0 / HW, s0 = n0 % HW;
  const float* base = in + (size_t)b * C_DIM * HW + s0;

  const int t = threadIdx.x, lane = t & 63, w = t >> 6;
  float acc = 0.f;
#pragma unroll
  for (int i = 0; i < 16; ++i) {
    float v = base[(size_t)(cc * 64 + w * 16 + i) * HW + lane];
    acc = fmaf(v, v, acc);
  }
  __shared__ float red[4][64];
  red[w][lane] = acc;
  __syncthreads();
  if (w == 0) {
    float tot = red[0][lane] + red[1][lane] + red[2][lane] + red[3][lane];
    atomicAdd(&ss[tensor * N_TOTAL + n0 + lane], tot);
  }
}

// ---------------------------------------------------------------------------
// Kernel 1b: normalize + transpose [B,C,HW] -> [N,C] f16. Same 512-block
// decomposition; 64ch x 64sp tile through padded LDS.
// ---------------------------------------------------------------------------
__global__ __launch_bounds__(256) void tr_kernel(
    const float* __restrict__ fq, const float* __restrict__ fk,
    const float* __restrict__ ss,
    _Float16* __restrict__ qh, _Float16* __restrict__ kh) {
  const int bid = blockIdx.x;
  const int tensor = bid >> 8;
  const int sp = (bid >> 2) & 63;
  const int cc = bid & 3;
  const float* in = tensor ? fk : fq;
  _Float16* out = tensor ? kh : qh;
  const int n0 = sp * 64;
  const int b = n0 / HW, s0 = n0 % HW;
  const float* base = in + (size_t)b * C_DIM * HW + s0;

  const int t = threadIdx.x, lane = t & 63, w = t >> 6;

  __shared__ float tile[64][65];
  __shared__ float sinv[64];
  if (w == 0) {
    float ssv = ss[tensor * N_TOTAL + n0 + lane];
    sinv[lane] = 1.0f / fmaxf(sqrtf(ssv), 1e-12f);  // eps = 1e-12
  }
#pragma unroll
  for (int i = 0; i < 16; ++i) {
    int cl = w * 16 + i;
    tile[cl][lane] = base[(size_t)(cc * 64 + cl) * HW + lane];
  }
  __syncthreads();
#pragma unroll
  for (int i = 0; i < 16; ++i) {
    int row = w * 16 + i;
    out[(size_t)(n0 + row) * C_DIM + cc * 64 + lane] =
        (_Float16)(tile[lane][row] * sinv[row]);
  }
}

// ---------------------------------------------------------------------------
// Kernel 2: per-row InfoNCE, register-staged for memory-level parallelism.
// One block per row. 32 dot-units of 8 lanes; ALL loads (4 idx + 4 q-chunks
// + 16 k-chunks + 4 pos-chunks) issued before any compute, static indices.
// ---------------------------------------------------------------------------
__global__ __launch_bounds__(256) void nce_kernel(
    const _Float16* __restrict__ qh, const _Float16* __restrict__ kh,
    const int* __restrict__ neg, float* __restrict__ out) {
  const int n = blockIdx.x;
  const int t = threadIdx.x;
  const int lane = t & 63;
  const int w = t >> 6;
  const int sub = lane & 7;              // lane within 8-lane dot group
  const int unit = w * 8 + (lane >> 3);  // 0..31

  __shared__ float sneg[K_NEG];
  __shared__ float s_lpos;

  // ---- stage indices (4 per unit) ----
  int r[4];
#pragma unroll
  for (int j = 0; j < 4; ++j) {
    int x = neg[(size_t)n * K_NEG + j * 32 + unit];
    r[j] = x + (x >= n ? 1 : 0);         // self-exclusion shift
  }
  // ---- stage q row chunk (channels sub*32..sub*32+32) ----
  const h8* qrow = (const h8*)(qh + (size_t)n * C_DIM) + sub * 4;
  h8 qv[4];
#pragma unroll
  for (int i = 0; i < 4; ++i) qv[i] = qrow[i];
  // ---- stage all 16 k chunks ----
  h8 kd[4][4];
#pragma unroll
  for (int j = 0; j < 4; ++j) {
    const h8* kr = (const h8*)(kh + (size_t)r[j] * C_DIM) + sub * 4;
#pragma unroll
    for (int i = 0; i < 4; ++i) kd[j][i] = kr[i];
  }
  // ---- stage positive row (unit 0 only) ----
  h8 kp[4];
  if (unit == 0) {
    const h8* kr = (const h8*)(kh + (size_t)n * C_DIM) + sub * 4;
#pragma unroll
    for (int i = 0; i < 4; ++i) kp[i] = kr[i];
  }

  // ---- convert q to f32 once ----
  float qf[32];
#pragma unroll
  for (int i = 0; i < 4; ++i)
#pragma unroll
    for (int j = 0; j < 8; ++j) qf[i * 8 + j] = (float)qv[i][j];

  // ---- compute 4 negative dots per unit ----
#pragma unroll
  for (int j = 0; j < 4; ++j) {
    float a0 = 0.f, a1 = 0.f;
#pragma unroll
    for (int i = 0; i < 4; ++i) {
#pragma unroll
      for (int e = 0; e < 8; e += 2) {
        a0 = fmaf((float)kd[j][i][e], qf[i * 8 + e], a0);
        a1 = fmaf((float)kd[j][i][e + 1], qf[i * 8 + e + 1], a1);
      }
    }
    float acc = a0 + a1;
    acc += __shfl_xor(acc, 1);
    acc += __shfl_xor(acc, 2);
    acc += __shfl_xor(acc, 4);
    if (sub == 0) sneg[j * 32 + unit] = acc;
  }
  // ---- positive dot ----
  if (unit == 0) {
    float a0 = 0.f, a1 = 0.f;
#pragma unroll
    for (int i = 0; i < 4; ++i) {
#pragma unroll
      for (int e = 0; e < 8; e += 2) {
        a0 = fmaf((float)kp[i][e], qf[i * 8 + e], a0);
        a1 = fmaf((float)kp[i][e + 1], qf[i * 8 + e + 1], a1);
      }
    }
    float acc = a0 + a1;
    acc += __shfl_xor(acc, 1);
    acc += __shfl_xor(acc, 2);
    acc += __shfl_xor(acc, 4);
    if (sub == 0) s_lpos = acc;
  }
  __syncthreads();

  // ---- wave 0: logsumexp over 129 logits ----
  if (w == 0) {
    float lp = s_lpos * TEMP_INV;
    float x1 = sneg[lane] * TEMP_INV;
    float x2 = sneg[lane + 64] * TEMP_INV;
    float m = fmaxf(fmaxf(x1, x2), lp);
#pragma unroll
    for (int off = 32; off; off >>= 1) m = fmaxf(m, __shfl_xor(m, off));
    float s = __expf(x1 - m) + __expf(x2 - m);
#pragma unroll
    for (int off = 32; off; off >>= 1) s += __shfl_xor(s, off);
    if (lane == 0) {
      s += __expf(lp - m);
      float loss = m + __logf(s) - lp;
      atomicAdd(out, loss * (1.0f / N_TOTAL));
    }
  }
}

extern "C" void kernel_launch(void* const* d_in, const int* in_sizes, int n_in,
                              void* d_out, int out_size, void* d_ws,
                              size_t ws_size, hipStream_t stream) {
  const float* fq = (const float*)d_in[0];
  const float* fk = (const float*)d_in[1];
  const int* neg = (const int*)d_in[2];
  float* out = (float*)d_out;

  _Float16* qh = (_Float16*)d_ws;                        // 2 MiB
  _Float16* kh = qh + (size_t)N_TOTAL * C_DIM;           // 2 MiB
  float* ss = (float*)(kh + (size_t)N_TOTAL * C_DIM);    // 32 KiB

  hipMemsetAsync(d_out, 0, sizeof(float), stream);
  hipMemsetAsync(ss, 0, 2 * N_TOTAL * sizeof(float), stream);
  hipLaunchKernelGGL(ss_kernel, dim3(512), dim3(256), 0, stream, fq, fk, ss);
  hipLaunchKernelGGL(tr_kernel, dim3(512), dim3(256), 0, stream,
                     fq, fk, ss, qh, kh);
  hipLaunchKernelGGL(nce_kernel, dim3(N_TOTAL), dim3(256), 0, stream,
                     qh, kh, neg, out);
}

// Round 4
// 93.057 us; speedup vs baseline: 1.4000x; 1.3526x over previous
//
#include <hip/hip_runtime.h>
#include <hip/hip_bf16.h>

#define N_TOTAL 4096
#define C_DIM 256
#define K_NEG 128
#define HW 1024
#define TEMP_INV (1.0f / 0.07f)

typedef _Float16 h8 __attribute__((ext_vector_type(8)));

// ---------------------------------------------------------------------------
// Kernel 1a: per-row sum of squares. 512 blocks = 2 tensors x 64 spatial
// chunks x 4 channel quarters. atomicAdd partials into ss[2][4096]
// (distinct addresses per row -> only 4-way contention, negligible).
// ---------------------------------------------------------------------------
__global__ __launch_bounds__(256) void ss_kernel(
    const float* __restrict__ fq, const float* __restrict__ fk,
    float* __restrict__ ss) {
  const int bid = blockIdx.x;
  const int tensor = bid >> 8;        // 0=q, 1=k
  const int sp = (bid >> 2) & 63;     // spatial chunk of 64 rows
  const int cc = bid & 3;             // channel quarter (64 channels)
  const float* in = tensor ? fk : fq;
  const int n0 = sp * 64;
  const int b = n0 / HW, s0 = n0 % HW;
  const float* base = in + (size_t)b * C_DIM * HW + s0;

  const int t = threadIdx.x, lane = t & 63, w = t >> 6;
  float acc = 0.f;
#pragma unroll
  for (int i = 0; i < 16; ++i) {
    float v = base[(size_t)(cc * 64 + w * 16 + i) * HW + lane];
    acc = fmaf(v, v, acc);
  }
  __shared__ float red[4][64];
  red[w][lane] = acc;
  __syncthreads();
  if (w == 0) {
    float tot = red[0][lane] + red[1][lane] + red[2][lane] + red[3][lane];
    atomicAdd(&ss[tensor * N_TOTAL + n0 + lane], tot);
  }
}

// ---------------------------------------------------------------------------
// Kernel 1b: normalize + transpose [B,C,HW] -> [N,C] f16. Same 512-block
// decomposition; 64ch x 64sp tile through padded LDS.
// ---------------------------------------------------------------------------
__global__ __launch_bounds__(256) void tr_kernel(
    const float* __restrict__ fq, const float* __restrict__ fk,
    const float* __restrict__ ss,
    _Float16* __restrict__ qh, _Float16* __restrict__ kh) {
  const int bid = blockIdx.x;
  const int tensor = bid >> 8;
  const int sp = (bid >> 2) & 63;
  const int cc = bid & 3;
  const float* in = tensor ? fk : fq;
  _Float16* out = tensor ? kh : qh;
  const int n0 = sp * 64;
  const int b = n0 / HW, s0 = n0 % HW;
  const float* base = in + (size_t)b * C_DIM * HW + s0;

  const int t = threadIdx.x, lane = t & 63, w = t >> 6;

  __shared__ float tile[64][65];
  __shared__ float sinv[64];
  if (w == 0) {
    float ssv = ss[tensor * N_TOTAL + n0 + lane];
    sinv[lane] = 1.0f / fmaxf(sqrtf(ssv), 1e-12f);  // eps = 1e-12
  }
#pragma unroll
  for (int i = 0; i < 16; ++i) {
    int cl = w * 16 + i;
    tile[cl][lane] = base[(size_t)(cc * 64 + cl) * HW + lane];
  }
  __syncthreads();
#pragma unroll
  for (int i = 0; i < 16; ++i) {
    int row = w * 16 + i;
    out[(size_t)(n0 + row) * C_DIM + cc * 64 + lane] =
        (_Float16)(tile[lane][row] * sinv[row]);
  }
}

// ---------------------------------------------------------------------------
// Kernel 2: per-row InfoNCE, register-staged. One block per row; per-row
// loss -> plain store to loss_buf[n] (NO shared atomic -- round-3 showed the
// 4096-deep same-address atomic chain was the 59us bottleneck).
// ---------------------------------------------------------------------------
__global__ __launch_bounds__(256) void nce_kernel(
    const _Float16* __restrict__ qh, const _Float16* __restrict__ kh,
    const int* __restrict__ neg, float* __restrict__ loss_buf) {
  const int n = blockIdx.x;
  const int t = threadIdx.x;
  const int lane = t & 63;
  const int w = t >> 6;
  const int sub = lane & 7;              // lane within 8-lane dot group
  const int unit = w * 8 + (lane >> 3);  // 0..31

  __shared__ float sneg[K_NEG];
  __shared__ float s_lpos;

  // ---- stage indices (4 per unit) ----
  int r[4];
#pragma unroll
  for (int j = 0; j < 4; ++j) {
    int x = neg[(size_t)n * K_NEG + j * 32 + unit];
    r[j] = x + (x >= n ? 1 : 0);         // self-exclusion shift
  }
  // ---- stage q row chunk (channels sub*32..sub*32+32) ----
  const h8* qrow = (const h8*)(qh + (size_t)n * C_DIM) + sub * 4;
  h8 qv[4];
#pragma unroll
  for (int i = 0; i < 4; ++i) qv[i] = qrow[i];
  // ---- stage all 16 k chunks ----
  h8 kd[4][4];
#pragma unroll
  for (int j = 0; j < 4; ++j) {
    const h8* kr = (const h8*)(kh + (size_t)r[j] * C_DIM) + sub * 4;
#pragma unroll
    for (int i = 0; i < 4; ++i) kd[j][i] = kr[i];
  }
  // ---- stage positive row (unit 0 only) ----
  h8 kp[4];
  if (unit == 0) {
    const h8* kr = (const h8*)(kh + (size_t)n * C_DIM) + sub * 4;
#pragma unroll
    for (int i = 0; i < 4; ++i) kp[i] = kr[i];
  }

  // ---- convert q to f32 once ----
  float qf[32];
#pragma unroll
  for (int i = 0; i < 4; ++i)
#pragma unroll
    for (int j = 0; j < 8; ++j) qf[i * 8 + j] = (float)qv[i][j];

  // ---- 4 negative dots per unit ----
#pragma unroll
  for (int j = 0; j < 4; ++j) {
    float a0 = 0.f, a1 = 0.f;
#pragma unroll
    for (int i = 0; i < 4; ++i) {
#pragma unroll
      for (int e = 0; e < 8; e += 2) {
        a0 = fmaf((float)kd[j][i][e], qf[i * 8 + e], a0);
        a1 = fmaf((float)kd[j][i][e + 1], qf[i * 8 + e + 1], a1);
      }
    }
    float acc = a0 + a1;
    acc += __shfl_xor(acc, 1);
    acc += __shfl_xor(acc, 2);
    acc += __shfl_xor(acc, 4);
    if (sub == 0) sneg[j * 32 + unit] = acc;
  }
  // ---- positive dot ----
  if (unit == 0) {
    float a0 = 0.f, a1 = 0.f;
#pragma unroll
    for (int i = 0; i < 4; ++i) {
#pragma unroll
      for (int e = 0; e < 8; e += 2) {
        a0 = fmaf((float)kp[i][e], qf[i * 8 + e], a0);
        a1 = fmaf((float)kp[i][e + 1], qf[i * 8 + e + 1], a1);
      }
    }
    float acc = a0 + a1;
    acc += __shfl_xor(acc, 1);
    acc += __shfl_xor(acc, 2);
    acc += __shfl_xor(acc, 4);
    if (sub == 0) s_lpos = acc;
  }
  __syncthreads();

  // ---- wave 0: logsumexp over 129 logits; plain store (no atomic) ----
  if (w == 0) {
    float lp = s_lpos * TEMP_INV;
    float x1 = sneg[lane] * TEMP_INV;
    float x2 = sneg[lane + 64] * TEMP_INV;
    float m = fmaxf(fmaxf(x1, x2), lp);
#pragma unroll
    for (int off = 32; off; off >>= 1) m = fmaxf(m, __shfl_xor(m, off));
    float s = __expf(x1 - m) + __expf(x2 - m);
#pragma unroll
    for (int off = 32; off; off >>= 1) s += __shfl_xor(s, off);
    if (lane == 0) loss_buf[n] = m + __logf(s) - lp;
  }
}

// ---------------------------------------------------------------------------
// Kernel 3: mean over 4096 per-row losses. One block, 1024 threads.
// ---------------------------------------------------------------------------
__global__ __launch_bounds__(1024) void reduce_kernel(
    const float* __restrict__ loss_buf, float* __restrict__ out) {
  const int t = threadIdx.x;
  const float4 v = ((const float4*)loss_buf)[t];
  float s = (v.x + v.y) + (v.z + v.w);
#pragma unroll
  for (int off = 32; off; off >>= 1) s += __shfl_xor(s, off);
  __shared__ float red[16];
  if ((t & 63) == 0) red[t >> 6] = s;
  __syncthreads();
  if (t < 16) {
    float x = red[t];
#pragma unroll
    for (int off = 8; off; off >>= 1) x += __shfl_xor(x, off);
    if (t == 0) out[0] = x * (1.0f / N_TOTAL);
  }
}

extern "C" void kernel_launch(void* const* d_in, const int* in_sizes, int n_in,
                              void* d_out, int out_size, void* d_ws,
                              size_t ws_size, hipStream_t stream) {
  const float* fq = (const float*)d_in[0];
  const float* fk = (const float*)d_in[1];
  const int* neg = (const int*)d_in[2];
  float* out = (float*)d_out;

  _Float16* qh = (_Float16*)d_ws;                        // 2 MiB
  _Float16* kh = qh + (size_t)N_TOTAL * C_DIM;           // 2 MiB
  float* ss = (float*)(kh + (size_t)N_TOTAL * C_DIM);    // 32 KiB
  float* loss_buf = ss + 2 * N_TOTAL;                    // 16 KiB

  hipMemsetAsync(ss, 0, 2 * N_TOTAL * sizeof(float), stream);
  hipLaunchKernelGGL(ss_kernel, dim3(512), dim3(256), 0, stream, fq, fk, ss);
  hipLaunchKernelGGL(tr_kernel, dim3(512), dim3(256), 0, stream,
                     fq, fk, ss, qh, kh);
  hipLaunchKernelGGL(nce_kernel, dim3(N_TOTAL), dim3(256), 0, stream,
                     qh, kh, neg, loss_buf);
  hipLaunchKernelGGL(reduce_kernel, dim3(1), dim3(1024), 0, stream,
                     loss_buf, out);
}

// Round 5
// 89.629 us; speedup vs baseline: 1.4536x; 1.0382x over previous
//
#include <hip/hip_runtime.h>
#include <hip/hip_bf16.h>

#define N_TOTAL 4096
#define C_DIM 256
#define K_NEG 128
#define HW 1024
#define TEMP_INV (1.0f / 0.07f)

typedef _Float16 h8 __attribute__((ext_vector_type(8)));

// ---------------------------------------------------------------------------
// Kernel 1 (fused): transpose [B,C,HW] -> [N,C] RAW f16 + per-row sumsq
// partials (atomicAdd into ss[2][4096]). Normalization is deferred to the
// nce kernel (dot_raw * invq * invk == dot of normalized rows).
// 512 blocks = 2 tensors x 64 spatial chunks x 4 channel quarters.
// ---------------------------------------------------------------------------
__global__ __launch_bounds__(256) void tr_ss_kernel(
    const float* __restrict__ fq, const float* __restrict__ fk,
    _Float16* __restrict__ qh, _Float16* __restrict__ kh,
    float* __restrict__ ss) {
  const int bid = blockIdx.x;
  const int tensor = bid >> 8;        // 0=q, 1=k
  const int sp = (bid >> 2) & 63;     // spatial chunk (64 rows)
  const int cc = bid & 3;             // channel quarter (64 channels)
  const float* in = tensor ? fk : fq;
  _Float16* out = tensor ? kh : qh;
  const int n0 = sp * 64;
  const int b = n0 / HW, s0 = n0 % HW;
  const float* base = in + (size_t)b * C_DIM * HW + s0;

  const int t = threadIdx.x, lane = t & 63, w = t >> 6;
  __shared__ float tile[64][65];
  __shared__ float red[4][64];

  // ---- load 64ch x 64sp tile, float4 along spatial (16B/lane coalesced) ----
  const int chl = t >> 4;             // 0..15
  const int sp4 = (t & 15) * 4;
#pragma unroll
  for (int p = 0; p < 4; ++p) {
    int cl = p * 16 + chl;
    const float4 v =
        *(const float4*)(base + (size_t)(cc * 64 + cl) * HW + sp4);
    tile[cl][sp4] = v.x; tile[cl][sp4 + 1] = v.y;
    tile[cl][sp4 + 2] = v.z; tile[cl][sp4 + 3] = v.w;
  }
  __syncthreads();

  // ---- per-row partial sum of squares over this channel quarter ----
  float acc = 0.f;
#pragma unroll
  for (int j = 0; j < 16; ++j) {
    float v = tile[w * 16 + j][lane];
    acc = fmaf(v, v, acc);
  }
  red[w][lane] = acc;
  __syncthreads();
  if (w == 0) {
    float tot = red[0][lane] + red[1][lane] + red[2][lane] + red[3][lane];
    atomicAdd(&ss[tensor * N_TOTAL + n0 + lane], tot);
  }

  // ---- transposed raw-f16 write: 32B contiguous per thread ----
  const int wsp = t >> 2, q4 = t & 3;
  h8 o0, o1;
#pragma unroll
  for (int j = 0; j < 8; ++j) o0[j] = (_Float16)tile[q4 * 16 + j][wsp];
#pragma unroll
  for (int j = 0; j < 8; ++j) o1[j] = (_Float16)tile[q4 * 16 + 8 + j][wsp];
  h8* dst = (h8*)(out + (size_t)(n0 + wsp) * C_DIM + cc * 64 + q4 * 16);
  dst[0] = o0;
  dst[1] = o1;
}

// ---------------------------------------------------------------------------
// Kernel 2: per-row InfoNCE, register-staged, CONTIGUOUS unit gathers.
// Lane `sub` owns channel chunks {sub, 8+sub, 16+sub, 24+sub} (h8 chunks),
// so each load instruction reads 128B contiguous per 8-lane unit.
// Normalization applied via invq*invk from the ss array. Plain store of
// per-row loss (no global atomic).
// ---------------------------------------------------------------------------
__global__ __launch_bounds__(256) void nce_kernel(
    const _Float16* __restrict__ qh, const _Float16* __restrict__ kh,
    const float* __restrict__ ss, const int* __restrict__ neg,
    float* __restrict__ loss_buf) {
  const int n = blockIdx.x;
  const int t = threadIdx.x;
  const int lane = t & 63;
  const int w = t >> 6;
  const int sub = lane & 7;              // lane within 8-lane dot group
  const int unit = w * 8 + (lane >> 3);  // 0..31

  __shared__ float sneg[K_NEG];
  __shared__ float s_lpos;

  const float* ssk_arr = ss + N_TOTAL;

  // ---- stage indices ----
  int r[4];
#pragma unroll
  for (int j = 0; j < 4; ++j) {
    int x = neg[(size_t)n * K_NEG + j * 32 + unit];
    r[j] = x + (x >= n ? 1 : 0);         // self-exclusion shift
  }
  // ---- stage q chunks ----
  const h8* qrow = (const h8*)(qh + (size_t)n * C_DIM);
  h8 qv[4];
#pragma unroll
  for (int i = 0; i < 4; ++i) qv[i] = qrow[i * 8 + sub];
  // ---- stage 16 k chunks (4 rows x 4 chunks) ----
  h8 kd[4][4];
#pragma unroll
  for (int j = 0; j < 4; ++j) {
    const h8* kr = (const h8*)(kh + (size_t)r[j] * C_DIM);
#pragma unroll
    for (int i = 0; i < 4; ++i) kd[j][i] = kr[i * 8 + sub];
  }
  // ---- stage norms ----
  float ssk[4];
#pragma unroll
  for (int j = 0; j < 4; ++j) ssk[j] = ssk_arr[r[j]];
  float ssq = ss[n];
  // ---- positive row (unit 0 only) ----
  h8 kp[4];
  float sskp = 1.f;
  if (unit == 0) {
    const h8* kr = (const h8*)(kh + (size_t)n * C_DIM);
#pragma unroll
    for (int i = 0; i < 4; ++i) kp[i] = kr[i * 8 + sub];
    sskp = ssk_arr[n];
  }

  // ---- q to f32 ----
  float qf[32];
#pragma unroll
  for (int i = 0; i < 4; ++i)
#pragma unroll
    for (int e = 0; e < 8; ++e) qf[i * 8 + e] = (float)qv[i][e];

  const float invq = 1.0f / fmaxf(sqrtf(ssq), 1e-12f);

  // ---- 4 negative dots per unit ----
#pragma unroll
  for (int j = 0; j < 4; ++j) {
    float a0 = 0.f, a1 = 0.f;
#pragma unroll
    for (int i = 0; i < 4; ++i)
#pragma unroll
      for (int e = 0; e < 8; e += 2) {
        a0 = fmaf((float)kd[j][i][e], qf[i * 8 + e], a0);
        a1 = fmaf((float)kd[j][i][e + 1], qf[i * 8 + e + 1], a1);
      }
    float acc = a0 + a1;
    acc += __shfl_xor(acc, 1);
    acc += __shfl_xor(acc, 2);
    acc += __shfl_xor(acc, 4);
    if (sub == 0) {
      float invk = 1.0f / fmaxf(sqrtf(ssk[j]), 1e-12f);
      sneg[j * 32 + unit] = acc * invq * invk;
    }
  }
  // ---- positive dot ----
  if (unit == 0) {
    float a0 = 0.f, a1 = 0.f;
#pragma unroll
    for (int i = 0; i < 4; ++i)
#pragma unroll
      for (int e = 0; e < 8; e += 2) {
        a0 = fmaf((float)kp[i][e], qf[i * 8 + e], a0);
        a1 = fmaf((float)kp[i][e + 1], qf[i * 8 + e + 1], a1);
      }
    float acc = a0 + a1;
    acc += __shfl_xor(acc, 1);
    acc += __shfl_xor(acc, 2);
    acc += __shfl_xor(acc, 4);
    if (sub == 0) {
      float invk = 1.0f / fmaxf(sqrtf(sskp), 1e-12f);
      s_lpos = acc * invq * invk;
    }
  }
  __syncthreads();

  // ---- wave 0: logsumexp over 129 logits; plain store ----
  if (w == 0) {
    float lp = s_lpos * TEMP_INV;
    float x1 = sneg[lane] * TEMP_INV;
    float x2 = sneg[lane + 64] * TEMP_INV;
    float m = fmaxf(fmaxf(x1, x2), lp);
#pragma unroll
    for (int off = 32; off; off >>= 1) m = fmaxf(m, __shfl_xor(m, off));
    float s = __expf(x1 - m) + __expf(x2 - m);
#pragma unroll
    for (int off = 32; off; off >>= 1) s += __shfl_xor(s, off);
    if (lane == 0) loss_buf[n] = m + __logf(s) - lp;
  }
}

// ---------------------------------------------------------------------------
// Kernel 3: mean over 4096 per-row losses. One block, 1024 threads.
// ---------------------------------------------------------------------------
__global__ __launch_bounds__(1024) void reduce_kernel(
    const float* __restrict__ loss_buf, float* __restrict__ out) {
  const int t = threadIdx.x;
  const float4 v = ((const float4*)loss_buf)[t];
  float s = (v.x + v.y) + (v.z + v.w);
#pragma unroll
  for (int off = 32; off; off >>= 1) s += __shfl_xor(s, off);
  __shared__ float red[16];
  if ((t & 63) == 0) red[t >> 6] = s;
  __syncthreads();
  if (t < 16) {
    float x = red[t];
#pragma unroll
    for (int off = 8; off; off >>= 1) x += __shfl_xor(x, off);
    if (t == 0) out[0] = x * (1.0f / N_TOTAL);
  }
}

extern "C" void kernel_launch(void* const* d_in, const int* in_sizes, int n_in,
                              void* d_out, int out_size, void* d_ws,
                              size_t ws_size, hipStream_t stream) {
  const float* fq = (const float*)d_in[0];
  const float* fk = (const float*)d_in[1];
  const int* neg = (const int*)d_in[2];
  float* out = (float*)d_out;

  _Float16* qh = (_Float16*)d_ws;                        // 2 MiB
  _Float16* kh = qh + (size_t)N_TOTAL * C_DIM;           // 2 MiB
  float* ss = (float*)(kh + (size_t)N_TOTAL * C_DIM);    // 32 KiB
  float* loss_buf = ss + 2 * N_TOTAL;                    // 16 KiB

  hipMemsetAsync(ss, 0, 2 * N_TOTAL * sizeof(float), stream);
  hipLaunchKernelGGL(tr_ss_kernel, dim3(512), dim3(256), 0, stream,
                     fq, fk, qh, kh, ss);
  hipLaunchKernelGGL(nce_kernel, dim3(N_TOTAL), dim3(256), 0, stream,
                     qh, kh, ss, neg, loss_buf);
  hipLaunchKernelGGL(reduce_kernel, dim3(1), dim3(1024), 0, stream,
                     loss_buf, out);
}

// Round 6
// 84.691 us; speedup vs baseline: 1.5383x; 1.0583x over previous
//
#include <hip/hip_runtime.h>
#include <hip/hip_bf16.h>

#define N_TOTAL 4096
#define C_DIM 256
#define K_NEG 128
#define HW 1024
#define TEMP_INV (1.0f / 0.07f)

typedef _Float16 h8 __attribute__((ext_vector_type(8)));
typedef _Float16 h2 __attribute__((ext_vector_type(2)));

// ---------------------------------------------------------------------------
// Kernel 1 (fused): transpose [B,C,HW] -> [N,C] RAW f16 + per-row sumsq
// partials (atomicAdd into ss[2][4096]). Normalization deferred to nce.
// 512 blocks = 2 tensors x 64 spatial chunks x 4 channel quarters.
// ---------------------------------------------------------------------------
__global__ __launch_bounds__(256) void tr_ss_kernel(
    const float* __restrict__ fq, const float* __restrict__ fk,
    _Float16* __restrict__ qh, _Float16* __restrict__ kh,
    float* __restrict__ ss) {
  const int bid = blockIdx.x;
  const int tensor = bid >> 8;        // 0=q, 1=k
  const int sp = (bid >> 2) & 63;     // spatial chunk (64 rows)
  const int cc = bid & 3;             // channel quarter (64 channels)
  const float* in = tensor ? fk : fq;
  _Float16* out = tensor ? kh : qh;
  const int n0 = sp * 64;
  const int b = n0 / HW, s0 = n0 % HW;
  const float* base = in + (size_t)b * C_DIM * HW + s0;

  const int t = threadIdx.x, lane = t & 63, w = t >> 6;
  __shared__ float tile[64][65];
  __shared__ float red[4][64];

  // ---- load 64ch x 64sp tile, float4 along spatial ----
  const int chl = t >> 4;             // 0..15
  const int sp4 = (t & 15) * 4;
#pragma unroll
  for (int p = 0; p < 4; ++p) {
    int cl = p * 16 + chl;
    const float4 v =
        *(const float4*)(base + (size_t)(cc * 64 + cl) * HW + sp4);
    tile[cl][sp4] = v.x; tile[cl][sp4 + 1] = v.y;
    tile[cl][sp4 + 2] = v.z; tile[cl][sp4 + 3] = v.w;
  }
  __syncthreads();

  // ---- per-row partial sum of squares over this channel quarter ----
  float acc = 0.f;
#pragma unroll
  for (int j = 0; j < 16; ++j) {
    float v = tile[w * 16 + j][lane];
    acc = fmaf(v, v, acc);
  }
  red[w][lane] = acc;
  __syncthreads();
  if (w == 0) {
    float tot = red[0][lane] + red[1][lane] + red[2][lane] + red[3][lane];
    atomicAdd(&ss[tensor * N_TOTAL + n0 + lane], tot);
  }

  // ---- transposed raw-f16 write: 32B contiguous per thread ----
  const int wsp = t >> 2, q4 = t & 3;
  h8 o0, o1;
#pragma unroll
  for (int j = 0; j < 8; ++j) o0[j] = (_Float16)tile[q4 * 16 + j][wsp];
#pragma unroll
  for (int j = 0; j < 8; ++j) o1[j] = (_Float16)tile[q4 * 16 + 8 + j][wsp];
  h8* dst = (h8*)(out + (size_t)(n0 + wsp) * C_DIM + cc * 64 + q4 * 16);
  dst[0] = o0;
  dst[1] = o1;
}

// ---------------------------------------------------------------------------
// Kernel 2: per-row InfoNCE. One block per row, 32 units of 8 lanes.
// ALL loads issued up front and PINNED with sched_barrier(0) -- round 5
// showed (VGPR_Count=68) that the compiler sinks the staged loads otherwise,
// leaving ~4 loads in flight and a latency-bound 30us kernel.
// Dots via v_dot2_f32_f16 (f32 accumulate -> same accuracy, half the VALU,
// no qf[32] register array).
// ---------------------------------------------------------------------------
__global__ __launch_bounds__(256) void nce_kernel(
    const _Float16* __restrict__ qh, const _Float16* __restrict__ kh,
    const float* __restrict__ ss, const int* __restrict__ neg,
    float* __restrict__ loss_buf) {
  const int n = blockIdx.x;
  const int t = threadIdx.x;
  const int lane = t & 63;
  const int w = t >> 6;
  const int sub = lane & 7;              // lane within 8-lane dot group
  const int unit = w * 8 + (lane >> 3);  // 0..31

  __shared__ float sneg[K_NEG];
  __shared__ float s_lpos;

  const float* ssk_arr = ss + N_TOTAL;

  // ===== issue ALL loads =====
  // indices first (they head the longest dependence chain)
  int r[4];
#pragma unroll
  for (int j = 0; j < 4; ++j) {
    int x = neg[(size_t)n * K_NEG + j * 32 + unit];
    r[j] = x + (x >= n ? 1 : 0);         // self-exclusion shift
  }
  // q chunks: lane sub owns h8 chunks {sub, 8+sub, 16+sub, 24+sub}
  const h8* qrow = (const h8*)(qh + (size_t)n * C_DIM);
  h8 qv[4];
#pragma unroll
  for (int i = 0; i < 4; ++i) qv[i] = qrow[i * 8 + sub];
  float ssq = ss[n];
  // positive row (unit 0 only)
  h8 kp[4];
  float sskp = 1.f;
  if (unit == 0) {
    const h8* kr = (const h8*)(kh + (size_t)n * C_DIM);
#pragma unroll
    for (int i = 0; i < 4; ++i) kp[i] = kr[i * 8 + sub];
    sskp = ssk_arr[n];
  }
  // 16 k chunks (4 negatives x 4 chunks) + 4 norms
  h8 kd[4][4];
  float ssk[4];
#pragma unroll
  for (int j = 0; j < 4; ++j) {
    const h8* kr = (const h8*)(kh + (size_t)r[j] * C_DIM);
#pragma unroll
    for (int i = 0; i < 4; ++i) kd[j][i] = kr[i * 8 + sub];
    ssk[j] = ssk_arr[r[j]];
  }
  // pin: nothing below may be hoisted above, no load may sink below
  __builtin_amdgcn_sched_barrier(0);

  const float invq = 1.0f / fmaxf(sqrtf(ssq), 1e-12f);

  union H { h8 v; h2 p[4]; };

  // ===== 4 negative dots per unit =====
#pragma unroll
  for (int j = 0; j < 4; ++j) {
    float a0 = 0.f, a1 = 0.f;
#pragma unroll
    for (int i = 0; i < 4; ++i) {
      H a; a.v = qv[i];
      H b; b.v = kd[j][i];
      a0 = __builtin_amdgcn_fdot2(b.p[0], a.p[0], a0, false);
      a1 = __builtin_amdgcn_fdot2(b.p[1], a.p[1], a1, false);
      a0 = __builtin_amdgcn_fdot2(b.p[2], a.p[2], a0, false);
      a1 = __builtin_amdgcn_fdot2(b.p[3], a.p[3], a1, false);
    }
    float acc = a0 + a1;
    acc += __shfl_xor(acc, 1);
    acc += __shfl_xor(acc, 2);
    acc += __shfl_xor(acc, 4);
    if (sub == 0) {
      float invk = 1.0f / fmaxf(sqrtf(ssk[j]), 1e-12f);
      sneg[j * 32 + unit] = acc * invq * invk;
    }
  }
  // ===== positive dot =====
  if (unit == 0) {
    float a0 = 0.f, a1 = 0.f;
#pragma unroll
    for (int i = 0; i < 4; ++i) {
      H a; a.v = qv[i];
      H b; b.v = kp[i];
      a0 = __builtin_amdgcn_fdot2(b.p[0], a.p[0], a0, false);
      a1 = __builtin_amdgcn_fdot2(b.p[1], a.p[1], a1, false);
      a0 = __builtin_amdgcn_fdot2(b.p[2], a.p[2], a0, false);
      a1 = __builtin_amdgcn_fdot2(b.p[3], a.p[3], a1, false);
    }
    float acc = a0 + a1;
    acc += __shfl_xor(acc, 1);
    acc += __shfl_xor(acc, 2);
    acc += __shfl_xor(acc, 4);
    if (sub == 0) {
      float invk = 1.0f / fmaxf(sqrtf(sskp), 1e-12f);
      s_lpos = acc * invq * invk;
    }
  }
  __syncthreads();

  // ===== wave 0: logsumexp over 129 logits; plain store =====
  if (w == 0) {
    float lp = s_lpos * TEMP_INV;
    float x1 = sneg[lane] * TEMP_INV;
    float x2 = sneg[lane + 64] * TEMP_INV;
    float m = fmaxf(fmaxf(x1, x2), lp);
#pragma unroll
    for (int off = 32; off; off >>= 1) m = fmaxf(m, __shfl_xor(m, off));
    float s = __expf(x1 - m) + __expf(x2 - m);
#pragma unroll
    for (int off = 32; off; off >>= 1) s += __shfl_xor(s, off);
    if (lane == 0) loss_buf[n] = m + __logf(s) - lp;
  }
}

// ---------------------------------------------------------------------------
// Kernel 3: mean over 4096 per-row losses. One block, 1024 threads.
// ---------------------------------------------------------------------------
__global__ __launch_bounds__(1024) void reduce_kernel(
    const float* __restrict__ loss_buf, float* __restrict__ out) {
  const int t = threadIdx.x;
  const float4 v = ((const float4*)loss_buf)[t];
  float s = (v.x + v.y) + (v.z + v.w);
#pragma unroll
  for (int off = 32; off; off >>= 1) s += __shfl_xor(s, off);
  __shared__ float red[16];
  if ((t & 63) == 0) red[t >> 6] = s;
  __syncthreads();
  if (t < 16) {
    float x = red[t];
#pragma unroll
    for (int off = 8; off; off >>= 1) x += __shfl_xor(x, off);
    if (t == 0) out[0] = x * (1.0f / N_TOTAL);
  }
}

extern "C" void kernel_launch(void* const* d_in, const int* in_sizes, int n_in,
                              void* d_out, int out_size, void* d_ws,
                              size_t ws_size, hipStream_t stream) {
  const float* fq = (const float*)d_in[0];
  const float* fk = (const float*)d_in[1];
  const int* neg = (const int*)d_in[2];
  float* out = (float*)d_out;

  _Float16* qh = (_Float16*)d_ws;                        // 2 MiB
  _Float16* kh = qh + (size_t)N_TOTAL * C_DIM;           // 2 MiB
  float* ss = (float*)(kh + (size_t)N_TOTAL * C_DIM);    // 32 KiB
  float* loss_buf = ss + 2 * N_TOTAL;                    // 16 KiB

  hipMemsetAsync(ss, 0, 2 * N_TOTAL * sizeof(float), stream);
  hipLaunchKernelGGL(tr_ss_kernel, dim3(512), dim3(256), 0, stream,
                     fq, fk, qh, kh, ss);
  hipLaunchKernelGGL(nce_kernel, dim3(N_TOTAL), dim3(256), 0, stream,
                     qh, kh, ss, neg, loss_buf);
  hipLaunchKernelGGL(reduce_kernel, dim3(1), dim3(1024), 0, stream,
                     loss_buf, out);
}